// Round 1
// baseline (341.043 us; speedup 1.0000x reference)
//
#include <hip/hip_runtime.h>
#include <hip/hip_bf16.h>
#include <math.h>

#define LOG2E 1.44269504088896340736f

typedef __attribute__((ext_vector_type(4))) float f32x4;
typedef __attribute__((ext_vector_type(8))) short bf16x8;
typedef __attribute__((ext_vector_type(4))) short bf16x4;
typedef __attribute__((ext_vector_type(4))) float float4_t;
typedef __attribute__((ext_vector_type(4))) int int4_t;

static __device__ __forceinline__ unsigned short f2b(float f){
  unsigned int u = __builtin_bit_cast(unsigned int, f);
  u = (u + 0x7FFFu + ((u >> 16) & 1u)) >> 16;
  return (unsigned short)u;
}

// ---------------- mask -> bitmask [2048][32] u64 ----------------
__global__ __launch_bounds__(256) void maskbits_kernel(const int* __restrict__ mask,
                                                       unsigned long long* __restrict__ out){
  int w = blockIdx.x * 256 + threadIdx.x;      // 0..65535, = t*32 + (s>>6)
  const int* p = mask + (size_t)w * 64;
  unsigned long long bits = 0ull;
  #pragma unroll
  for (int j = 0; j < 64; j += 4){
    int4_t v4 = *(const int4_t*)(p + j);
    if (v4[0]) bits |= (1ull << (j + 0));
    if (v4[1]) bits |= (1ull << (j + 1));
    if (v4[2]) bits |= (1ull << (j + 2));
    if (v4[3]) bits |= (1ull << (j + 3));
  }
  out[w] = bits;
}

// ---------------- GEMM: C[m,n] = sum_k A[m,k]*W[n,k] + bias[n] ----------------
// AMODE 0: A fp32; AMODE 1: A bf16.
// OMODE 0: bf16 out scattered to [b*16+h][t][64] head layout; OMODE 1: fp32 linear out.
template<int AMODE, int OMODE>
__global__ __launch_bounds__(256) void gemm_kernel(const void* __restrict__ Aptr,
    const float* __restrict__ W, const float* __restrict__ bias, void* __restrict__ Cptr)
{
  __shared__ short As[128][40];   // +8 pad: 80B row stride -> conflict-free b128 frag reads
  __shared__ short Wsh[128][40];
  const int tid = threadIdx.x;
  const int m0 = blockIdx.x * 128;
  const int n0 = blockIdx.y * 128;
  const int lane = tid & 63, wid = tid >> 6;
  const int wm = wid >> 1, wn = wid & 1;
  const int r16 = lane & 15, kg = lane >> 4;
  const float* Af = (const float*)Aptr;
  const unsigned short* Ab = (const unsigned short*)Aptr;

  f32x4 acc[4][4];
  const f32x4 z4 = {0.f, 0.f, 0.f, 0.f};
  #pragma unroll
  for (int i = 0; i < 4; ++i)
    #pragma unroll
    for (int j = 0; j < 4; ++j) acc[i][j] = z4;

  for (int k0 = 0; k0 < 1024; k0 += 32) {
    #pragma unroll
    for (int i = 0; i < 4; ++i){
      int c = tid + i * 256;                  // 0..1023
      int row = c >> 3, kq = (c & 7) * 4;
      float4_t wv = *(const float4_t*)(W + (size_t)(n0 + row) * 1024 + k0 + kq);
      bf16x4 wb; wb[0]=f2b(wv[0]); wb[1]=f2b(wv[1]); wb[2]=f2b(wv[2]); wb[3]=f2b(wv[3]);
      *(bf16x4*)&Wsh[row][kq] = wb;
    }
    if (AMODE == 0){
      #pragma unroll
      for (int i = 0; i < 4; ++i){
        int c = tid + i * 256;
        int row = c >> 3, kq = (c & 7) * 4;
        float4_t av = *(const float4_t*)(Af + (size_t)(m0 + row) * 1024 + k0 + kq);
        bf16x4 ab; ab[0]=f2b(av[0]); ab[1]=f2b(av[1]); ab[2]=f2b(av[2]); ab[3]=f2b(av[3]);
        *(bf16x4*)&As[row][kq] = ab;
      }
    } else {
      #pragma unroll
      for (int i = 0; i < 2; ++i){
        int c = tid + i * 256;                // 0..511
        int row = c >> 2, kq = (c & 3) * 8;
        bf16x8 av = *(const bf16x8*)(Ab + (size_t)(m0 + row) * 1024 + k0 + kq);
        *(bf16x8*)&As[row][kq] = av;
      }
    }
    __syncthreads();
    bf16x8 af[4], wf[4];
    #pragma unroll
    for (int mi = 0; mi < 4; ++mi) af[mi] = *(const bf16x8*)&As[wm*64 + mi*16 + r16][kg*8];
    #pragma unroll
    for (int ni = 0; ni < 4; ++ni) wf[ni] = *(const bf16x8*)&Wsh[wn*64 + ni*16 + r16][kg*8];
    #pragma unroll
    for (int mi = 0; mi < 4; ++mi)
      #pragma unroll
      for (int ni = 0; ni < 4; ++ni)
        acc[mi][ni] = __builtin_amdgcn_mfma_f32_16x16x32_bf16(af[mi], wf[ni], acc[mi][ni], 0, 0, 0);
    __syncthreads();
  }

  #pragma unroll
  for (int mi = 0; mi < 4; ++mi){
    #pragma unroll
    for (int ni = 0; ni < 4; ++ni){
      int m = m0 + wm*64 + mi*16 + kg*4;
      int n = n0 + wn*64 + ni*16 + r16;
      float bv = bias[n];
      #pragma unroll
      for (int r = 0; r < 4; ++r){
        float v = acc[mi][ni][r] + bv;
        int mm = m + r;
        if (OMODE == 0){
          int bb = mm >> 11, t = mm & 2047, hh = n >> 6, d = n & 63;
          ((unsigned short*)Cptr)[(((size_t)(bb*16 + hh) * 2048 + t) << 6) + d] = f2b(v);
        } else {
          ((float*)Cptr)[(size_t)mm * 1024 + n] = v;
        }
      }
    }
  }
}

// ---------------- flash attention ----------------
// grid (T/64, B*H), 256 thr = 4 waves x 16 q-rows. KV chunks of 64 staged in LDS.
__global__ __launch_bounds__(256) void attn_kernel(const unsigned short* __restrict__ qh,
    const unsigned short* __restrict__ kh, const unsigned short* __restrict__ vh,
    const unsigned long long* __restrict__ mbits, unsigned short* __restrict__ attnout)
{
  __shared__ short Ks[64][72];   // [s][d], +8 pad
  __shared__ short Vs[64][72];   // [d][s] (transposed at stage time)
  __shared__ short Ps[64][72];   // [t][s] per-wave 16-row stripes
  const int tid = threadIdx.x, lane = tid & 63, wid = tid >> 6;
  const int bh = blockIdx.y;
  const int b = bh >> 4, h = bh & 15;
  const int t0 = blockIdx.x * 64;
  const int tw = t0 + wid * 16;
  const int r16 = lane & 15, kg = lane >> 4;

  const unsigned short* qrow = qh + ((size_t)bh * 2048 + tw + r16) * 64;
  bf16x8 aq0 = *(const bf16x8*)(qrow + kg * 8);
  bf16x8 aq1 = *(const bf16x8*)(qrow + 32 + kg * 8);

  float m_r[4], l_r[4];
  f32x4 o[4];
  const f32x4 z4 = {0.f, 0.f, 0.f, 0.f};
  #pragma unroll
  for (int r = 0; r < 4; ++r){ m_r[r] = -INFINITY; l_r[r] = 0.f; }
  #pragma unroll
  for (int df = 0; df < 4; ++df) o[df] = z4;

  const unsigned short* kbase = kh + (size_t)bh * 2048 * 64;
  const unsigned short* vbase = vh + (size_t)bh * 2048 * 64;

  for (int s0 = 0; s0 < 2048; s0 += 64) {
    // stage K [s][d] and V transposed [d][s]
    #pragma unroll
    for (int i = 0; i < 2; ++i){
      int c = tid + i * 256;                 // 0..511
      int row = c >> 3, d0 = (c & 7) * 8;
      bf16x8 kv = *(const bf16x8*)(kbase + (size_t)(s0 + row) * 64 + d0);
      *(bf16x8*)&Ks[row][d0] = kv;
      bf16x8 vv = *(const bf16x8*)(vbase + (size_t)(s0 + row) * 64 + d0);
      #pragma unroll
      for (int j = 0; j < 8; ++j) Vs[d0 + j][row] = vv[j];
    }
    __syncthreads();

    // QK^T: 16 t-rows x 64 s-cols per wave
    f32x4 sfr[4];
    #pragma unroll
    for (int sb = 0; sb < 4; ++sb){
      bf16x8 bk0 = *(const bf16x8*)&Ks[sb*16 + r16][kg*8];
      bf16x8 bk1 = *(const bf16x8*)&Ks[sb*16 + r16][32 + kg*8];
      f32x4 z = z4;
      z = __builtin_amdgcn_mfma_f32_16x16x32_bf16(aq0, bk0, z, 0, 0, 0);
      z = __builtin_amdgcn_mfma_f32_16x16x32_bf16(aq1, bk1, z, 0, 0, 0);
      sfr[sb] = z;
    }

    // mask + scale (replace with -10000 where mask bit set — matches reference)
    unsigned long long mw[4];
    #pragma unroll
    for (int r = 0; r < 4; ++r)
      mw[r] = mbits[(size_t)(tw + kg*4 + r) * 32 + (s0 >> 6)];
    #pragma unroll
    for (int sb = 0; sb < 4; ++sb)
      #pragma unroll
      for (int r = 0; r < 4; ++r){
        float sv = sfr[sb][r] * 0.125f;
        int sc = sb * 16 + r16;
        if ((mw[r] >> sc) & 1ull) sv = -10000.f;
        sfr[sb][r] = sv;
      }

    // row max across 4 frags + 16 lanes
    float mx[4];
    #pragma unroll
    for (int r = 0; r < 4; ++r)
      mx[r] = fmaxf(fmaxf(sfr[0][r], sfr[1][r]), fmaxf(sfr[2][r], sfr[3][r]));
    #pragma unroll
    for (int off = 1; off <= 8; off <<= 1)
      #pragma unroll
      for (int r = 0; r < 4; ++r) mx[r] = fmaxf(mx[r], __shfl_xor(mx[r], off));

    float corr[4], rs[4];
    #pragma unroll
    for (int r = 0; r < 4; ++r){
      float mn = fmaxf(m_r[r], mx[r]);
      corr[r] = exp2f((m_r[r] - mn) * LOG2E);
      m_r[r] = mn;
    }
    #pragma unroll
    for (int sb = 0; sb < 4; ++sb)
      #pragma unroll
      for (int r = 0; r < 4; ++r)
        sfr[sb][r] = exp2f((sfr[sb][r] - m_r[r]) * LOG2E);
    #pragma unroll
    for (int r = 0; r < 4; ++r)
      rs[r] = sfr[0][r] + sfr[1][r] + sfr[2][r] + sfr[3][r];
    #pragma unroll
    for (int off = 1; off <= 8; off <<= 1)
      #pragma unroll
      for (int r = 0; r < 4; ++r) rs[r] += __shfl_xor(rs[r], off);
    #pragma unroll
    for (int r = 0; r < 4; ++r) l_r[r] = l_r[r] * corr[r] + rs[r];
    #pragma unroll
    for (int df = 0; df < 4; ++df)
      #pragma unroll
      for (int r = 0; r < 4; ++r) o[df][r] *= corr[r];

    // P -> LDS (bf16), per-wave private stripe
    #pragma unroll
    for (int sb = 0; sb < 4; ++sb)
      #pragma unroll
      for (int r = 0; r < 4; ++r)
        Ps[wid*16 + kg*4 + r][sb*16 + r16] = (short)f2b(sfr[sb][r]);

    // PV: o[t][d] += P[t][s] * V[s][d]
    bf16x8 pa0 = *(const bf16x8*)&Ps[wid*16 + r16][kg*8];
    bf16x8 pa1 = *(const bf16x8*)&Ps[wid*16 + r16][32 + kg*8];
    #pragma unroll
    for (int df = 0; df < 4; ++df){
      bf16x8 bv0 = *(const bf16x8*)&Vs[df*16 + r16][kg*8];
      bf16x8 bv1 = *(const bf16x8*)&Vs[df*16 + r16][32 + kg*8];
      o[df] = __builtin_amdgcn_mfma_f32_16x16x32_bf16(pa0, bv0, o[df], 0, 0, 0);
      o[df] = __builtin_amdgcn_mfma_f32_16x16x32_bf16(pa1, bv1, o[df], 0, 0, 0);
    }
    __syncthreads();
  }

  // epilogue: normalize, write [b*T+t][E] bf16
  #pragma unroll
  for (int r = 0; r < 4; ++r) l_r[r] = 1.0f / l_r[r];
  #pragma unroll
  for (int df = 0; df < 4; ++df)
    #pragma unroll
    for (int r = 0; r < 4; ++r){
      int t = tw + kg*4 + r;
      int col = h*64 + df*16 + r16;
      attnout[(size_t)(b * 2048 + t) * 1024 + col] = (short)f2b(o[df][r] * l_r[r]);
    }
}

// ---------------- launch ----------------
extern "C" void kernel_launch(void* const* d_in, const int* in_sizes, int n_in,
                              void* d_out, int out_size, void* d_ws, size_t ws_size,
                              hipStream_t stream) {
  const float* q    = (const float*)d_in[0];
  const float* k    = (const float*)d_in[1];
  const float* v    = (const float*)d_in[2];
  const int*   mask = (const int*)d_in[3];
  const float* Wq = (const float*)d_in[4];  const float* bq = (const float*)d_in[5];
  const float* Wk = (const float*)d_in[6];  const float* bk = (const float*)d_in[7];
  const float* Wv = (const float*)d_in[8];  const float* bv = (const float*)d_in[9];
  const float* Wo = (const float*)d_in[10]; const float* bo = (const float*)d_in[11];
  float* out = (float*)d_out;

  char* ws = (char*)d_ws;
  unsigned short* qh    = (unsigned short*)(ws);                 // 8 MB  [B*H][T][64]
  unsigned short* kh    = (unsigned short*)(ws + 8388608);       // 8 MB  [B*H][S][64]
  unsigned short* vh    = (unsigned short*)(ws + 16777216);      // 8 MB  [B*H][S][64]
  unsigned short* attno = (unsigned short*)(ws + 25165824);      // 8 MB  [B*T][E]
  unsigned long long* mbits = (unsigned long long*)(ws + 33554432); // 512 KB

  maskbits_kernel<<<256, 256, 0, stream>>>(mask, mbits);

  dim3 gg(32, 8);
  gemm_kernel<0, 0><<<gg, 256, 0, stream>>>(q, Wq, bq, qh);
  gemm_kernel<0, 0><<<gg, 256, 0, stream>>>(k, Wk, bk, kh);
  gemm_kernel<0, 0><<<gg, 256, 0, stream>>>(v, Wv, bv, vh);

  dim3 ga(32, 32);
  attn_kernel<<<ga, 256, 0, stream>>>(qh, kh, vh, mbits, attno);

  gemm_kernel<1, 1><<<gg, 256, 0, stream>>>(attno, Wo, bo, out);
}

// Round 2
// 280.529 us; speedup vs baseline: 1.2157x; 1.2157x over previous
//
#include <hip/hip_runtime.h>
#include <hip/hip_bf16.h>
#include <math.h>

#define LOG2E 1.44269504088896340736f

typedef __attribute__((ext_vector_type(4))) float f32x4;
typedef __attribute__((ext_vector_type(8))) short bf16x8;
typedef __attribute__((ext_vector_type(4))) short bf16x4;
typedef __attribute__((ext_vector_type(4))) float float4_t;
typedef __attribute__((ext_vector_type(4))) int int4_t;

typedef const __attribute__((address_space(1))) void gbl_cvoid;
typedef __attribute__((address_space(3))) void lds_void;

static __device__ __forceinline__ void gload16(const void* g, void* l){
  __builtin_amdgcn_global_load_lds((gbl_cvoid*)g, (lds_void*)l, 16, 0, 0);
}

static __device__ __forceinline__ unsigned short f2b(float f){
  unsigned int u = __builtin_bit_cast(unsigned int, f);
  u = (u + 0x7FFFu + ((u >> 16) & 1u)) >> 16;
  return (unsigned short)u;
}

// ---------------- mask -> bitmask [2048][32] u64 ----------------
__global__ __launch_bounds__(256) void maskbits_kernel(const int* __restrict__ mask,
                                                       unsigned long long* __restrict__ out){
  int w = blockIdx.x * 256 + threadIdx.x;      // 0..65535, = t*32 + (s>>6)
  const int* p = mask + (size_t)w * 64;
  unsigned long long bits = 0ull;
  #pragma unroll
  for (int j = 0; j < 64; j += 4){
    int4_t v4 = *(const int4_t*)(p + j);
    if (v4[0]) bits |= (1ull << (j + 0));
    if (v4[1]) bits |= (1ull << (j + 1));
    if (v4[2]) bits |= (1ull << (j + 2));
    if (v4[3]) bits |= (1ull << (j + 3));
  }
  out[w] = bits;
}

// ---------------- fp32 -> bf16 conversion (7 tensors in one dispatch) ----------------
struct CvtArgs { const float* src[7]; unsigned short* dst[7]; };

__global__ __launch_bounds__(256) void cvt_kernel(CvtArgs a){
  int y = blockIdx.y;
  int n4 = (y < 3) ? (4194304/4) : (1048576/4);
  int idx = blockIdx.x * 256 + threadIdx.x;
  if (idx >= n4) return;
  float4_t v = *(const float4_t*)(a.src[y] + (size_t)idx * 4);
  bf16x4 b; b[0]=(short)f2b(v[0]); b[1]=(short)f2b(v[1]); b[2]=(short)f2b(v[2]); b[3]=(short)f2b(v[3]);
  *(bf16x4*)(a.dst[y] + (size_t)idx * 4) = b;
}

// ---------------- bf16 GEMM: C[m,n] = sum_k A[m,k]*W[n,k] + bias[n] ----------------
// MODE 0: fused QKV (grid.y=24, sel=y>>3); sel 0/1 -> head layout [bh][t][64] bf16,
//         sel 2 -> transposed head layout [bh][d][2048] bf16.
// MODE 1: O-projection (grid.y=8), fp32 linear out.
struct GemmArgs { const unsigned short* A[3]; const unsigned short* W[3];
                  const float* bias[3]; void* C[3]; };

template<int MODE>
__global__ __launch_bounds__(256) void gemm_kernel(GemmArgs ga)
{
  __shared__ unsigned short As[128*32];
  __shared__ unsigned short Ws[128*32];
  const int tid = threadIdx.x, lane = tid & 63, wid = tid >> 6;
  const int sel = (MODE == 0) ? (blockIdx.y >> 3) : 0;
  const int n0  = (MODE == 0) ? ((blockIdx.y & 7) * 128) : (blockIdx.y * 128);
  const int m0  = blockIdx.x * 128;
  const unsigned short* A = ga.A[sel];
  const unsigned short* W = ga.W[sel];
  const float* bias = ga.bias[sel];
  const int wm = wid >> 1, wn = wid & 1;
  const int r16 = lane & 15, kg = lane >> 4;
  const int srow = wid * 16 + (lane >> 2);   // staging row base within 64-row half
  const int sch  = lane & 3;                 // 8-elem chunk within 32-k row

  f32x4 acc[4][4];
  const f32x4 z4 = {0.f, 0.f, 0.f, 0.f};
  #pragma unroll
  for (int i = 0; i < 4; ++i)
    #pragma unroll
    for (int j = 0; j < 4; ++j) acc[i][j] = z4;

  for (int k0 = 0; k0 < 1024; k0 += 32) {
    #pragma unroll
    for (int i = 0; i < 2; ++i){
      int row = i * 64 + srow;
      gload16(A + (size_t)(m0 + row) * 1024 + k0 + sch * 8, (char*)As + i * 4096 + wid * 1024);
      gload16(W + (size_t)(n0 + row) * 1024 + k0 + sch * 8, (char*)Ws + i * 4096 + wid * 1024);
    }
    __syncthreads();
    bf16x8 af[4], wf[4];
    #pragma unroll
    for (int mi = 0; mi < 4; ++mi) af[mi] = *(const bf16x8*)(As + (wm*64 + mi*16 + r16)*32 + kg*8);
    #pragma unroll
    for (int ni = 0; ni < 4; ++ni) wf[ni] = *(const bf16x8*)(Ws + (wn*64 + ni*16 + r16)*32 + kg*8);
    #pragma unroll
    for (int mi = 0; mi < 4; ++mi)
      #pragma unroll
      for (int ni = 0; ni < 4; ++ni)
        acc[mi][ni] = __builtin_amdgcn_mfma_f32_16x16x32_bf16(af[mi], wf[ni], acc[mi][ni], 0, 0, 0);
    __syncthreads();
  }

  #pragma unroll
  for (int mi = 0; mi < 4; ++mi){
    #pragma unroll
    for (int ni = 0; ni < 4; ++ni){
      int m = m0 + wm*64 + mi*16 + kg*4;
      int n = n0 + wn*64 + ni*16 + r16;
      float bv = bias[n];
      #pragma unroll
      for (int r = 0; r < 4; ++r){
        float v = acc[mi][ni][r] + bv;
        int mm = m + r;
        if (MODE == 1){
          ((float*)ga.C[0])[(size_t)mm * 1024 + n] = v;
        } else {
          int bb = mm >> 11, t = mm & 2047, hh = n >> 6, d = n & 63;
          if (sel < 2)
            ((unsigned short*)ga.C[sel])[(((size_t)(bb*16 + hh) * 2048 + t) << 6) + d] = f2b(v);
          else
            ((unsigned short*)ga.C[2])[((size_t)(bb*16 + hh) * 64 + d) * 2048 + t] = f2b(v);
        }
      }
    }
  }
}

// ---------------- flash attention ----------------
// grid (T/128, B*H), 256 thr = 4 waves x 32 q-rows. KV chunks of 64.
__global__ __launch_bounds__(256) void attn_kernel(const unsigned short* __restrict__ qh,
    const unsigned short* __restrict__ kh, const unsigned short* __restrict__ vhT,
    const unsigned long long* __restrict__ mbits, unsigned short* __restrict__ attnout)
{
  __shared__ short Ks[64][68];    // [s][d], PAD=68
  __shared__ short Vs[64][68];    // [d][s], PAD=68 (V comes pre-transposed)
  __shared__ short Ps[128][68];   // [t][s], per-wave 32-row stripes, PAD=68
  const int tid = threadIdx.x, lane = tid & 63, wid = tid >> 6;
  const int bh = blockIdx.y;
  const int b = bh >> 4, h = bh & 15;
  const int t0 = blockIdx.x * 128;
  const int tw = t0 + wid * 32;
  const int r16 = lane & 15, kg = lane >> 4;

  // Q fragments: rows tw + mi*16 + r16
  const unsigned short* qbase = qh + ((size_t)bh * 2048 + tw) * 64;
  bf16x8 aq[2][2];
  #pragma unroll
  for (int mi = 0; mi < 2; ++mi)
    #pragma unroll
    for (int kh2 = 0; kh2 < 2; ++kh2)
      aq[mi][kh2] = *(const bf16x8*)(qbase + (size_t)(mi*16 + r16) * 64 + kh2*32 + kg*8);

  float m_r[8], l_r[8];           // [mi*4 + r]
  f32x4 o[2][4];                  // [mi][df]
  const f32x4 z4 = {0.f, 0.f, 0.f, 0.f};
  #pragma unroll
  for (int q8 = 0; q8 < 8; ++q8){ m_r[q8] = -INFINITY; l_r[q8] = 0.f; }
  #pragma unroll
  for (int mi = 0; mi < 2; ++mi)
    #pragma unroll
    for (int df = 0; df < 4; ++df) o[mi][df] = z4;

  const unsigned short* kbase = kh + (size_t)bh * 2048 * 64;
  const unsigned short* vtb   = vhT + (size_t)bh * 64 * 2048;
  const size_t mbase = (size_t)(tw + kg * 4) * 32;

  const int srow = tid >> 3, sch = tid & 7;   // staging: 512 jobs over 2 iters

  for (int s0 = 0; s0 < 2048; s0 += 64) {
    #pragma unroll
    for (int i = 0; i < 2; ++i){
      int row = i * 32 + srow;
      *(bf16x8*)&Ks[row][sch * 8] = *(const bf16x8*)(kbase + (size_t)(s0 + row) * 64 + sch * 8);
      *(bf16x8*)&Vs[row][sch * 8] = *(const bf16x8*)(vtb + (size_t)row * 2048 + s0 + sch * 8);
    }
    __syncthreads();

    // QK^T: 32 t-rows x 64 s-cols per wave
    f32x4 sfr[2][4];
    #pragma unroll
    for (int mi = 0; mi < 2; ++mi)
      #pragma unroll
      for (int sb = 0; sb < 4; ++sb){
        bf16x8 bk0 = *(const bf16x8*)&Ks[sb*16 + r16][kg*8];
        bf16x8 bk1 = *(const bf16x8*)&Ks[sb*16 + r16][32 + kg*8];
        f32x4 z = z4;
        z = __builtin_amdgcn_mfma_f32_16x16x32_bf16(aq[mi][0], bk0, z, 0, 0, 0);
        z = __builtin_amdgcn_mfma_f32_16x16x32_bf16(aq[mi][1], bk1, z, 0, 0, 0);
        sfr[mi][sb] = z;
      }

    // mask + scale
    const int cw = s0 >> 6;
    #pragma unroll
    for (int mi = 0; mi < 2; ++mi)
      #pragma unroll
      for (int r = 0; r < 4; ++r){
        unsigned long long mwr = mbits[mbase + (size_t)(mi*16 + r) * 32 + cw] >> r16;
        #pragma unroll
        for (int sb = 0; sb < 4; ++sb){
          float sv = sfr[mi][sb][r] * 0.125f;
          if ((mwr >> (sb * 16)) & 1ull) sv = -10000.f;
          sfr[mi][sb][r] = sv;
        }
      }

    // online softmax over the 64-col chunk (rows: q8 = mi*4+r)
    #pragma unroll
    for (int mi = 0; mi < 2; ++mi){
      float mx[4], rs[4], corr[4];
      #pragma unroll
      for (int r = 0; r < 4; ++r)
        mx[r] = fmaxf(fmaxf(sfr[mi][0][r], sfr[mi][1][r]), fmaxf(sfr[mi][2][r], sfr[mi][3][r]));
      #pragma unroll
      for (int off = 1; off <= 8; off <<= 1)
        #pragma unroll
        for (int r = 0; r < 4; ++r) mx[r] = fmaxf(mx[r], __shfl_xor(mx[r], off));
      #pragma unroll
      for (int r = 0; r < 4; ++r){
        float mn = fmaxf(m_r[mi*4+r], mx[r]);
        corr[r] = exp2f((m_r[mi*4+r] - mn) * LOG2E);
        m_r[mi*4+r] = mn;
      }
      #pragma unroll
      for (int sb = 0; sb < 4; ++sb)
        #pragma unroll
        for (int r = 0; r < 4; ++r)
          sfr[mi][sb][r] = exp2f((sfr[mi][sb][r] - m_r[mi*4+r]) * LOG2E);
      #pragma unroll
      for (int r = 0; r < 4; ++r)
        rs[r] = sfr[mi][0][r] + sfr[mi][1][r] + sfr[mi][2][r] + sfr[mi][3][r];
      #pragma unroll
      for (int off = 1; off <= 8; off <<= 1)
        #pragma unroll
        for (int r = 0; r < 4; ++r) rs[r] += __shfl_xor(rs[r], off);
      #pragma unroll
      for (int r = 0; r < 4; ++r) l_r[mi*4+r] = l_r[mi*4+r] * corr[r] + rs[r];
      #pragma unroll
      for (int df = 0; df < 4; ++df)
        #pragma unroll
        for (int r = 0; r < 4; ++r) o[mi][df][r] *= corr[r];
      // P -> LDS (bf16): rows wid*32 + mi*16 + kg*4 + r, col sb*16 + r16 (PAD=68: conflict-free)
      #pragma unroll
      for (int sb = 0; sb < 4; ++sb)
        #pragma unroll
        for (int r = 0; r < 4; ++r)
          Ps[wid*32 + mi*16 + kg*4 + r][sb*16 + r16] = (short)f2b(sfr[mi][sb][r]);
    }

    // PV: o[t][d] += P[t][s] * V[s][d]  (B-frag from Vs[d][s] rows, contiguous along s)
    #pragma unroll
    for (int mi = 0; mi < 2; ++mi){
      bf16x8 pa0 = *(const bf16x8*)&Ps[wid*32 + mi*16 + r16][kg*8];
      bf16x8 pa1 = *(const bf16x8*)&Ps[wid*32 + mi*16 + r16][32 + kg*8];
      #pragma unroll
      for (int df = 0; df < 4; ++df){
        bf16x8 bv0 = *(const bf16x8*)&Vs[df*16 + r16][kg*8];
        bf16x8 bv1 = *(const bf16x8*)&Vs[df*16 + r16][32 + kg*8];
        o[mi][df] = __builtin_amdgcn_mfma_f32_16x16x32_bf16(pa0, bv0, o[mi][df], 0, 0, 0);
        o[mi][df] = __builtin_amdgcn_mfma_f32_16x16x32_bf16(pa1, bv1, o[mi][df], 0, 0, 0);
      }
    }
    __syncthreads();
  }

  // epilogue: normalize, write [b*T+t][E] bf16
  #pragma unroll
  for (int q8 = 0; q8 < 8; ++q8) l_r[q8] = 1.0f / l_r[q8];
  #pragma unroll
  for (int mi = 0; mi < 2; ++mi)
    #pragma unroll
    for (int df = 0; df < 4; ++df)
      #pragma unroll
      for (int r = 0; r < 4; ++r){
        int t = tw + mi*16 + kg*4 + r;
        int col = h*64 + df*16 + r16;
        attnout[(size_t)(b * 2048 + t) * 1024 + col] = (short)f2b(o[mi][df][r] * l_r[mi*4+r]);
      }
}

// ---------------- launch ----------------
extern "C" void kernel_launch(void* const* d_in, const int* in_sizes, int n_in,
                              void* d_out, int out_size, void* d_ws, size_t ws_size,
                              hipStream_t stream) {
  const float* q    = (const float*)d_in[0];
  const float* k    = (const float*)d_in[1];
  const float* v    = (const float*)d_in[2];
  const int*   mask = (const int*)d_in[3];
  const float* Wq = (const float*)d_in[4];  const float* bq = (const float*)d_in[5];
  const float* Wk = (const float*)d_in[6];  const float* bk = (const float*)d_in[7];
  const float* Wv = (const float*)d_in[8];  const float* bv = (const float*)d_in[9];
  const float* Wo = (const float*)d_in[10]; const float* bo = (const float*)d_in[11];

  char* ws = (char*)d_ws;
  unsigned short* qb   = (unsigned short*)(ws);                   // 8 MB [4096][1024] bf16
  unsigned short* kb   = (unsigned short*)(ws + 8388608);         // 8 MB
  unsigned short* vb   = (unsigned short*)(ws + 16777216);        // 8 MB
  unsigned short* Wqb  = (unsigned short*)(ws + 25165824);        // 2 MB
  unsigned short* Wkb  = (unsigned short*)(ws + 27262976);        // 2 MB
  unsigned short* Wvb  = (unsigned short*)(ws + 29360128);        // 2 MB
  unsigned short* Wob  = (unsigned short*)(ws + 31457280);        // 2 MB
  unsigned short* qhd  = (unsigned short*)(ws + 33554432);        // 8 MB [bh][t][64]
  unsigned short* khd  = (unsigned short*)(ws + 41943040);        // 8 MB [bh][s][64]
  unsigned short* vhT  = (unsigned short*)(ws + 50331648);        // 8 MB [bh][64][2048]
  unsigned long long* mbits = (unsigned long long*)(ws + 58720256); // 512 KB
  unsigned short* attno = qb;   // alias: qb dead after QKV GEMM

  maskbits_kernel<<<256, 256, 0, stream>>>(mask, mbits);

  CvtArgs ca;
  ca.src[0]=q;  ca.dst[0]=qb;  ca.src[1]=k;  ca.dst[1]=kb;  ca.src[2]=v;  ca.dst[2]=vb;
  ca.src[3]=Wq; ca.dst[3]=Wqb; ca.src[4]=Wk; ca.dst[4]=Wkb;
  ca.src[5]=Wv; ca.dst[5]=Wvb; ca.src[6]=Wo; ca.dst[6]=Wob;
  cvt_kernel<<<dim3(4096, 7), 256, 0, stream>>>(ca);

  GemmArgs g0;
  g0.A[0]=qb; g0.A[1]=kb; g0.A[2]=vb;
  g0.W[0]=Wqb; g0.W[1]=Wkb; g0.W[2]=Wvb;
  g0.bias[0]=bq; g0.bias[1]=bk; g0.bias[2]=bv;
  g0.C[0]=qhd; g0.C[1]=khd; g0.C[2]=vhT;
  gemm_kernel<0><<<dim3(32, 24), 256, 0, stream>>>(g0);

  attn_kernel<<<dim3(16, 32), 256, 0, stream>>>(qhd, khd, vhT, mbits, attno);

  GemmArgs g1;
  g1.A[0]=attno; g1.A[1]=attno; g1.A[2]=attno;
  g1.W[0]=Wob; g1.W[1]=Wob; g1.W[2]=Wob;
  g1.bias[0]=bo; g1.bias[1]=bo; g1.bias[2]=bo;
  g1.C[0]=d_out; g1.C[1]=d_out; g1.C[2]=d_out;
  gemm_kernel<1><<<dim3(32, 8), 256, 0, stream>>>(g1);
}

// Round 3
// 205.506 us; speedup vs baseline: 1.6595x; 1.3651x over previous
//
#include <hip/hip_runtime.h>
#include <hip/hip_bf16.h>
#include <math.h>

#define LOG2E 1.44269504088896340736f

typedef __attribute__((ext_vector_type(4))) float f32x4;
typedef __attribute__((ext_vector_type(8))) short bf16x8;
typedef __attribute__((ext_vector_type(4))) short bf16x4;
typedef __attribute__((ext_vector_type(4))) float float4_t;
typedef __attribute__((ext_vector_type(4))) int int4_t;

typedef const __attribute__((address_space(1))) void gbl_cvoid;
typedef __attribute__((address_space(3))) void lds_void;

static __device__ __forceinline__ void gload16(const void* g, void* l){
  __builtin_amdgcn_global_load_lds((gbl_cvoid*)g, (lds_void*)l, 16, 0, 0);
}

static __device__ __forceinline__ unsigned short f2b(float f){
  unsigned int u = __builtin_bit_cast(unsigned int, f);
  u = (u + 0x7FFFu + ((u >> 16) & 1u)) >> 16;
  return (unsigned short)u;
}

// ---------------- mask -> bitmask [2048][32] u64 ----------------
__global__ __launch_bounds__(256) void maskbits_kernel(const int* __restrict__ mask,
                                                       unsigned long long* __restrict__ out){
  int w = blockIdx.x * 256 + threadIdx.x;      // 0..65535, = t*32 + (s>>6)
  const int* p = mask + (size_t)w * 64;
  unsigned long long bits = 0ull;
  #pragma unroll
  for (int j = 0; j < 64; j += 4){
    int4_t v4 = *(const int4_t*)(p + j);
    if (v4[0]) bits |= (1ull << (j + 0));
    if (v4[1]) bits |= (1ull << (j + 1));
    if (v4[2]) bits |= (1ull << (j + 2));
    if (v4[3]) bits |= (1ull << (j + 3));
  }
  out[w] = bits;
}

// ---------------- fp32 -> bf16 conversion (7 tensors in one dispatch) ----------------
struct CvtArgs { const float* src[7]; unsigned short* dst[7]; };

__global__ __launch_bounds__(256) void cvt_kernel(CvtArgs a){
  int y = blockIdx.y;
  int n4 = (y < 3) ? (4194304/4) : (1048576/4);
  int idx = blockIdx.x * 256 + threadIdx.x;
  if (idx >= n4) return;
  float4_t v = *(const float4_t*)(a.src[y] + (size_t)idx * 4);
  bf16x4 b; b[0]=(short)f2b(v[0]); b[1]=(short)f2b(v[1]); b[2]=(short)f2b(v[2]); b[3]=(short)f2b(v[3]);
  *(bf16x4*)(a.dst[y] + (size_t)idx * 4) = b;
}

// ---------------- bf16 GEMM: C[m,n] = sum_k A[m,k]*W[n,k] + bias[n] ----------------
struct GemmArgs { const unsigned short* A[3]; const unsigned short* W[3];
                  const float* bias[3]; void* C[3]; };

template<int MODE>
__global__ __launch_bounds__(256) void gemm_kernel(GemmArgs ga)
{
  __shared__ unsigned short As[128*32];
  __shared__ unsigned short Ws[128*32];
  const int tid = threadIdx.x, lane = tid & 63, wid = tid >> 6;
  const int sel = (MODE == 0) ? (blockIdx.y >> 3) : 0;
  const int n0  = (MODE == 0) ? ((blockIdx.y & 7) * 128) : (blockIdx.y * 128);
  const int m0  = blockIdx.x * 128;
  const unsigned short* A = ga.A[sel];
  const unsigned short* W = ga.W[sel];
  const float* bias = ga.bias[sel];
  const int wm = wid >> 1, wn = wid & 1;
  const int r16 = lane & 15, kg = lane >> 4;
  const int srow = wid * 16 + (lane >> 2);
  const int sch  = lane & 3;

  f32x4 acc[4][4];
  const f32x4 z4 = {0.f, 0.f, 0.f, 0.f};
  #pragma unroll
  for (int i = 0; i < 4; ++i)
    #pragma unroll
    for (int j = 0; j < 4; ++j) acc[i][j] = z4;

  for (int k0 = 0; k0 < 1024; k0 += 32) {
    #pragma unroll
    for (int i = 0; i < 2; ++i){
      int row = i * 64 + srow;
      gload16(A + (size_t)(m0 + row) * 1024 + k0 + sch * 8, (char*)As + i * 4096 + wid * 1024);
      gload16(W + (size_t)(n0 + row) * 1024 + k0 + sch * 8, (char*)Ws + i * 4096 + wid * 1024);
    }
    __syncthreads();
    bf16x8 af[4], wf[4];
    #pragma unroll
    for (int mi = 0; mi < 4; ++mi) af[mi] = *(const bf16x8*)(As + (wm*64 + mi*16 + r16)*32 + kg*8);
    #pragma unroll
    for (int ni = 0; ni < 4; ++ni) wf[ni] = *(const bf16x8*)(Ws + (wn*64 + ni*16 + r16)*32 + kg*8);
    #pragma unroll
    for (int mi = 0; mi < 4; ++mi)
      #pragma unroll
      for (int ni = 0; ni < 4; ++ni)
        acc[mi][ni] = __builtin_amdgcn_mfma_f32_16x16x32_bf16(af[mi], wf[ni], acc[mi][ni], 0, 0, 0);
    __syncthreads();
  }

  #pragma unroll
  for (int mi = 0; mi < 4; ++mi){
    #pragma unroll
    for (int ni = 0; ni < 4; ++ni){
      int m = m0 + wm*64 + mi*16 + kg*4;
      int n = n0 + wn*64 + ni*16 + r16;
      float bv = bias[n];
      #pragma unroll
      for (int r = 0; r < 4; ++r){
        float v = acc[mi][ni][r] + bv;
        int mm = m + r;
        if (MODE == 1){
          ((float*)ga.C[0])[(size_t)mm * 1024 + n] = v;
        } else {
          int bb = mm >> 11, t = mm & 2047, hh = n >> 6, d = n & 63;
          if (sel < 2)
            ((unsigned short*)ga.C[sel])[(((size_t)(bb*16 + hh) * 2048 + t) << 6) + d] = f2b(v);
          else
            ((unsigned short*)ga.C[2])[((size_t)(bb*16 + hh) * 64 + d) * 2048 + t] = f2b(v);
        }
      }
    }
  }
}

// ---------------- flash attention ----------------
// grid (T/128, B*H), 512 thr = 8 waves x 16 q-rows. KV chunks of 64,
// double-buffered via global_load_lds with XOR chunk-swizzle (c ^= row&7).
__global__ __launch_bounds__(512) void attn_kernel(const unsigned short* __restrict__ qh,
    const unsigned short* __restrict__ kh, const unsigned short* __restrict__ vhT,
    const unsigned long long* __restrict__ mbits, unsigned short* __restrict__ attnout)
{
  __shared__ short Ks[2][64][64];   // [buf][s][d], physical chunk = logical ^ (s&7)
  __shared__ short Vs[2][64][64];   // [buf][d][s], physical chunk = logical ^ (d&7)
  __shared__ short Ps[128][64];     // [t][s], per-wave 16-row stripes, same swizzle
  const int tid = threadIdx.x, lane = tid & 63, wid = tid >> 6;
  const int bh = blockIdx.y;
  const int b = bh >> 4, h = bh & 15;
  const int t0 = blockIdx.x * 128;
  const int tw = t0 + wid * 16;
  const int r16 = lane & 15, kg = lane >> 4;
  const int x7 = r16 & 7;                    // row&7 for all frag reads (rows = 16*i + r16)
  const int ph0 = (kg ^ x7) * 8;             // physical offset of logical chunk kg
  const int ph1 = ((kg + 4) ^ x7) * 8;       // physical offset of logical chunk kg+4

  // staging geometry: slot tid covers row tid>>3, physical chunk tid&7
  const int sR = tid >> 3;                   // 0..63
  const int sL = (tid & 7) ^ (sR & 7);       // logical (global) chunk for this slot

  const unsigned short* kbase = kh + (size_t)bh * 2048 * 64;
  const unsigned short* vtb   = vhT + (size_t)bh * 64 * 2048;
  const unsigned short* qbase = qh + ((size_t)bh * 2048 + tw) * 64;

  bf16x8 aq[2];
  aq[0] = *(const bf16x8*)(qbase + (size_t)r16 * 64 + kg * 8);
  aq[1] = *(const bf16x8*)(qbase + (size_t)r16 * 64 + 32 + kg * 8);

  float m_r[4], l_r[4];
  f32x4 o[4];
  const f32x4 z4 = {0.f, 0.f, 0.f, 0.f};
  #pragma unroll
  for (int r = 0; r < 4; ++r){ m_r[r] = -INFINITY; l_r[r] = 0.f; }
  #pragma unroll
  for (int df = 0; df < 4; ++df) o[df] = z4;

  const size_t mbase = (size_t)(tw + kg * 4) * 32;

  // prologue: stage chunk 0 into buf 0
  gload16(kbase + (size_t)sR * 64 + sL * 8, (char*)Ks + wid * 1024);
  gload16(vtb + (size_t)sR * 2048 + sL * 8, (char*)Vs + wid * 1024);
  __syncthreads();

  for (int c = 0; c < 32; ++c) {
    const int cur = c & 1;
    const int s0n = (c + 1) * 64;
    if (c + 1 < 32) {   // issue next-chunk stage; overlaps with compute below
      gload16(kbase + (size_t)(s0n + sR) * 64 + sL * 8, (char*)Ks + (cur ^ 1) * 8192 + wid * 1024);
      gload16(vtb + (size_t)sR * 2048 + s0n + sL * 8, (char*)Vs + (cur ^ 1) * 8192 + wid * 1024);
    }

    // QK^T: 16 t-rows x 64 s-cols per wave
    f32x4 sfr[4];
    __builtin_amdgcn_s_setprio(1);
    #pragma unroll
    for (int sb = 0; sb < 4; ++sb){
      bf16x8 bk0 = *(const bf16x8*)&Ks[cur][sb*16 + r16][ph0];
      bf16x8 bk1 = *(const bf16x8*)&Ks[cur][sb*16 + r16][ph1];
      f32x4 z = z4;
      z = __builtin_amdgcn_mfma_f32_16x16x32_bf16(aq[0], bk0, z, 0, 0, 0);
      z = __builtin_amdgcn_mfma_f32_16x16x32_bf16(aq[1], bk1, z, 0, 0, 0);
      sfr[sb] = z;
    }
    __builtin_amdgcn_s_setprio(0);

    // mask + scale
    const int cw = c;
    float mx[4], rs[4], corr[4];
    #pragma unroll
    for (int r = 0; r < 4; ++r){
      unsigned long long mwr = mbits[mbase + (size_t)r * 32 + cw] >> r16;
      #pragma unroll
      for (int sb = 0; sb < 4; ++sb){
        float sv = sfr[sb][r] * 0.125f;
        if ((mwr >> (sb * 16)) & 1ull) sv = -10000.f;
        sfr[sb][r] = sv;
      }
    }

    // online softmax over the 64-col chunk
    #pragma unroll
    for (int r = 0; r < 4; ++r)
      mx[r] = fmaxf(fmaxf(sfr[0][r], sfr[1][r]), fmaxf(sfr[2][r], sfr[3][r]));
    #pragma unroll
    for (int off = 1; off <= 8; off <<= 1)
      #pragma unroll
      for (int r = 0; r < 4; ++r) mx[r] = fmaxf(mx[r], __shfl_xor(mx[r], off));
    #pragma unroll
    for (int r = 0; r < 4; ++r){
      float mn = fmaxf(m_r[r], mx[r]);
      corr[r] = exp2f((m_r[r] - mn) * LOG2E);
      m_r[r] = mn;
    }
    #pragma unroll
    for (int sb = 0; sb < 4; ++sb)
      #pragma unroll
      for (int r = 0; r < 4; ++r)
        sfr[sb][r] = exp2f((sfr[sb][r] - m_r[r]) * LOG2E);
    #pragma unroll
    for (int r = 0; r < 4; ++r)
      rs[r] = sfr[0][r] + sfr[1][r] + sfr[2][r] + sfr[3][r];
    #pragma unroll
    for (int off = 1; off <= 8; off <<= 1)
      #pragma unroll
      for (int r = 0; r < 4; ++r) rs[r] += __shfl_xor(rs[r], off);
    #pragma unroll
    for (int r = 0; r < 4; ++r) l_r[r] = l_r[r] * corr[r] + rs[r];
    #pragma unroll
    for (int df = 0; df < 4; ++df)
      #pragma unroll
      for (int r = 0; r < 4; ++r) o[df][r] *= corr[r];

    // P -> LDS (bf16), swizzled: row = wid*16 + kg*4 + r, logical chunk = 2*sb + (r16>>3)
    #pragma unroll
    for (int sb = 0; sb < 4; ++sb)
      #pragma unroll
      for (int r = 0; r < 4; ++r){
        int prow = wid*16 + kg*4 + r;
        int pc = (2*sb + (r16 >> 3)) ^ (prow & 7);
        Ps[prow][pc * 8 + (r16 & 7)] = (short)f2b(sfr[sb][r]);
      }

    // PV: o[t][d] += P[t][s] * V[s][d]
    bf16x8 pa0 = *(const bf16x8*)&Ps[wid*16 + r16][ph0];
    bf16x8 pa1 = *(const bf16x8*)&Ps[wid*16 + r16][ph1];
    __builtin_amdgcn_s_setprio(1);
    #pragma unroll
    for (int df = 0; df < 4; ++df){
      bf16x8 bv0 = *(const bf16x8*)&Vs[cur][df*16 + r16][ph0];
      bf16x8 bv1 = *(const bf16x8*)&Vs[cur][df*16 + r16][ph1];
      o[df] = __builtin_amdgcn_mfma_f32_16x16x32_bf16(pa0, bv0, o[df], 0, 0, 0);
      o[df] = __builtin_amdgcn_mfma_f32_16x16x32_bf16(pa1, bv1, o[df], 0, 0, 0);
    }
    __builtin_amdgcn_s_setprio(0);

    __syncthreads();   // drains next-chunk loads + releases buf for c+2
  }

  // epilogue: normalize, write [b*T+t][E] bf16
  #pragma unroll
  for (int r = 0; r < 4; ++r) l_r[r] = 1.0f / l_r[r];
  #pragma unroll
  for (int df = 0; df < 4; ++df)
    #pragma unroll
    for (int r = 0; r < 4; ++r){
      int t = tw + kg*4 + r;
      int col = h*64 + df*16 + r16;
      attnout[(size_t)(b * 2048 + t) * 1024 + col] = (short)f2b(o[df][r] * l_r[r]);
    }
}

// ---------------- launch ----------------
extern "C" void kernel_launch(void* const* d_in, const int* in_sizes, int n_in,
                              void* d_out, int out_size, void* d_ws, size_t ws_size,
                              hipStream_t stream) {
  const float* q    = (const float*)d_in[0];
  const float* k    = (const float*)d_in[1];
  const float* v    = (const float*)d_in[2];
  const int*   mask = (const int*)d_in[3];
  const float* Wq = (const float*)d_in[4];  const float* bq = (const float*)d_in[5];
  const float* Wk = (const float*)d_in[6];  const float* bk = (const float*)d_in[7];
  const float* Wv = (const float*)d_in[8];  const float* bv = (const float*)d_in[9];
  const float* Wo = (const float*)d_in[10]; const float* bo = (const float*)d_in[11];

  char* ws = (char*)d_ws;
  unsigned short* qb   = (unsigned short*)(ws);                   // 8 MB [4096][1024] bf16
  unsigned short* kb   = (unsigned short*)(ws + 8388608);         // 8 MB
  unsigned short* vb   = (unsigned short*)(ws + 16777216);        // 8 MB
  unsigned short* Wqb  = (unsigned short*)(ws + 25165824);        // 2 MB
  unsigned short* Wkb  = (unsigned short*)(ws + 27262976);        // 2 MB
  unsigned short* Wvb  = (unsigned short*)(ws + 29360128);        // 2 MB
  unsigned short* Wob  = (unsigned short*)(ws + 31457280);        // 2 MB
  unsigned short* qhd  = (unsigned short*)(ws + 33554432);        // 8 MB [bh][t][64]
  unsigned short* khd  = (unsigned short*)(ws + 41943040);        // 8 MB [bh][s][64]
  unsigned short* vhT  = (unsigned short*)(ws + 50331648);        // 8 MB [bh][64][2048]
  unsigned long long* mbits = (unsigned long long*)(ws + 58720256); // 512 KB
  unsigned short* attno = qb;   // alias: qb dead after QKV GEMM

  maskbits_kernel<<<256, 256, 0, stream>>>(mask, mbits);

  CvtArgs ca;
  ca.src[0]=q;  ca.dst[0]=qb;  ca.src[1]=k;  ca.dst[1]=kb;  ca.src[2]=v;  ca.dst[2]=vb;
  ca.src[3]=Wq; ca.dst[3]=Wqb; ca.src[4]=Wk; ca.dst[4]=Wkb;
  ca.src[5]=Wv; ca.dst[5]=Wvb; ca.src[6]=Wo; ca.dst[6]=Wob;
  cvt_kernel<<<dim3(4096, 7), 256, 0, stream>>>(ca);

  GemmArgs g0;
  g0.A[0]=qb; g0.A[1]=kb; g0.A[2]=vb;
  g0.W[0]=Wqb; g0.W[1]=Wkb; g0.W[2]=Wvb;
  g0.bias[0]=bq; g0.bias[1]=bk; g0.bias[2]=bv;
  g0.C[0]=qhd; g0.C[1]=khd; g0.C[2]=vhT;
  gemm_kernel<0><<<dim3(32, 24), 256, 0, stream>>>(g0);

  attn_kernel<<<dim3(16, 32), 512, 0, stream>>>(qhd, khd, vhT, mbits, attno);

  GemmArgs g1;
  g1.A[0]=attno; g1.A[1]=attno; g1.A[2]=attno;
  g1.W[0]=Wob; g1.W[1]=Wob; g1.W[2]=Wob;
  g1.bias[0]=bo; g1.bias[1]=bo; g1.bias[2]=bo;
  g1.C[0]=d_out; g1.C[1]=d_out; g1.C[2]=d_out;
  gemm_kernel<1><<<dim3(32, 8), 256, 0, stream>>>(g1);
}

// Round 4
// 172.405 us; speedup vs baseline: 1.9782x; 1.1920x over previous
//
#include <hip/hip_runtime.h>
#include <hip/hip_bf16.h>
#include <math.h>

#define LOG2E 1.44269504088896340736f
#define QSCALE 0.18033688011112042f   /* 0.125 * log2(e) */
#define MASKVAL -14426.950408889634f  /* -10000 * log2(e) */

typedef __attribute__((ext_vector_type(4))) float f32x4;
typedef __attribute__((ext_vector_type(8))) short bf16x8;
typedef __attribute__((ext_vector_type(4))) short bf16x4;
typedef __attribute__((ext_vector_type(4))) float float4_t;
typedef __attribute__((ext_vector_type(4))) int int4_t;
typedef __attribute__((ext_vector_type(2))) unsigned int uint2_t;

typedef const __attribute__((address_space(1))) void gbl_cvoid;
typedef __attribute__((address_space(3))) void lds_void;

static __device__ __forceinline__ void gload16(const void* g, void* l){
  __builtin_amdgcn_global_load_lds((gbl_cvoid*)g, (lds_void*)l, 16, 0, 0);
}

static __device__ __forceinline__ unsigned short f2b(float f){
  unsigned int u = __builtin_bit_cast(unsigned int, f);
  u = (u + 0x7FFFu + ((u >> 16) & 1u)) >> 16;
  return (unsigned short)u;
}

static __device__ __forceinline__ unsigned int cvtpk_bf16(float a, float b){
  unsigned int r;
  asm("v_cvt_pk_bf16_f32 %0, %1, %2" : "=v"(r) : "v"(a), "v"(b));
  return r;
}

// ---------------- mask -> bitmask [2048][32] u64 ----------------
__global__ __launch_bounds__(256) void maskbits_kernel(const int* __restrict__ mask,
                                                       unsigned long long* __restrict__ out){
  int w = blockIdx.x * 256 + threadIdx.x;      // 0..65535, = t*32 + (s>>6)
  const int* p = mask + (size_t)w * 64;
  unsigned long long bits = 0ull;
  #pragma unroll
  for (int j = 0; j < 64; j += 4){
    int4_t v4 = *(const int4_t*)(p + j);
    if (v4[0]) bits |= (1ull << (j + 0));
    if (v4[1]) bits |= (1ull << (j + 1));
    if (v4[2]) bits |= (1ull << (j + 2));
    if (v4[3]) bits |= (1ull << (j + 3));
  }
  out[w] = bits;
}

// ---------------- fp32 -> bf16 conversion (7 tensors in one dispatch) ----------------
struct CvtArgs { const float* src[7]; unsigned short* dst[7]; };

__global__ __launch_bounds__(256) void cvt_kernel(CvtArgs a){
  int y = blockIdx.y;
  int n4 = (y < 3) ? (4194304/4) : (1048576/4);
  int idx = blockIdx.x * 256 + threadIdx.x;
  if (idx >= n4) return;
  float4_t v = *(const float4_t*)(a.src[y] + (size_t)idx * 4);
  bf16x4 b; b[0]=(short)f2b(v[0]); b[1]=(short)f2b(v[1]); b[2]=(short)f2b(v[2]); b[3]=(short)f2b(v[3]);
  *(bf16x4*)(a.dst[y] + (size_t)idx * 4) = b;
}

// ---------------- bf16 GEMM: C[m,n] = sum_k A[m,k]*W[n,k] + bias[n] ----------------
struct GemmArgs { const unsigned short* A[3]; const unsigned short* W[3];
                  const float* bias[3]; void* C[3]; };

template<int MODE>
__global__ __launch_bounds__(256) void gemm_kernel(GemmArgs ga)
{
  __shared__ unsigned short As[128*32];
  __shared__ unsigned short Ws[128*32];
  const int tid = threadIdx.x, lane = tid & 63, wid = tid >> 6;
  const int sel = (MODE == 0) ? (blockIdx.y >> 3) : 0;
  const int n0  = (MODE == 0) ? ((blockIdx.y & 7) * 128) : (blockIdx.y * 128);
  const int m0  = blockIdx.x * 128;
  const unsigned short* A = ga.A[sel];
  const unsigned short* W = ga.W[sel];
  const float* bias = ga.bias[sel];
  const int wm = wid >> 1, wn = wid & 1;
  const int r16 = lane & 15, kg = lane >> 4;
  const int srow = wid * 16 + (lane >> 2);
  const int sch  = lane & 3;

  f32x4 acc[4][4];
  const f32x4 z4 = {0.f, 0.f, 0.f, 0.f};
  #pragma unroll
  for (int i = 0; i < 4; ++i)
    #pragma unroll
    for (int j = 0; j < 4; ++j) acc[i][j] = z4;

  for (int k0 = 0; k0 < 1024; k0 += 32) {
    #pragma unroll
    for (int i = 0; i < 2; ++i){
      int row = i * 64 + srow;
      gload16(A + (size_t)(m0 + row) * 1024 + k0 + sch * 8, (char*)As + i * 4096 + wid * 1024);
      gload16(W + (size_t)(n0 + row) * 1024 + k0 + sch * 8, (char*)Ws + i * 4096 + wid * 1024);
    }
    __syncthreads();
    bf16x8 af[4], wf[4];
    #pragma unroll
    for (int mi = 0; mi < 4; ++mi) af[mi] = *(const bf16x8*)(As + (wm*64 + mi*16 + r16)*32 + kg*8);
    #pragma unroll
    for (int ni = 0; ni < 4; ++ni) wf[ni] = *(const bf16x8*)(Ws + (wn*64 + ni*16 + r16)*32 + kg*8);
    #pragma unroll
    for (int mi = 0; mi < 4; ++mi)
      #pragma unroll
      for (int ni = 0; ni < 4; ++ni)
        acc[mi][ni] = __builtin_amdgcn_mfma_f32_16x16x32_bf16(af[mi], wf[ni], acc[mi][ni], 0, 0, 0);
    __syncthreads();
  }

  #pragma unroll
  for (int mi = 0; mi < 4; ++mi){
    #pragma unroll
    for (int ni = 0; ni < 4; ++ni){
      int m = m0 + wm*64 + mi*16 + kg*4;
      int n = n0 + wn*64 + ni*16 + r16;
      float bv = bias[n];
      #pragma unroll
      for (int r = 0; r < 4; ++r){
        float v = acc[mi][ni][r] + bv;
        if (MODE == 0 && sel == 0) v *= QSCALE;   // fold 0.125*log2e into Q
        int mm = m + r;
        if (MODE == 1){
          ((float*)ga.C[0])[(size_t)mm * 1024 + n] = v;
        } else {
          int bb = mm >> 11, t = mm & 2047, hh = n >> 6, d = n & 63;
          if (sel < 2)
            ((unsigned short*)ga.C[sel])[(((size_t)(bb*16 + hh) * 2048 + t) << 6) + d] = f2b(v);
          else
            ((unsigned short*)ga.C[2])[((size_t)(bb*16 + hh) * 64 + d) * 2048 + t] = f2b(v);
        }
      }
    }
  }
}

// ---------------- flash attention ----------------
// grid (T/128, B*H), 512 thr = 8 waves x 16 q-rows. KV chunks of 64,
// double-buffered global_load_lds, XOR chunk-swizzle, SWAPPED QK^T:
// S^T = mfma(K_frag, Q_frag) so each lane holds one full q-row -> in-register softmax.
__global__ __launch_bounds__(512) void attn_kernel(const unsigned short* __restrict__ qh,
    const unsigned short* __restrict__ kh, const unsigned short* __restrict__ vhT,
    const unsigned long long* __restrict__ mbits, unsigned short* __restrict__ attnout)
{
  __shared__ short Ks[2][64][64];   // [buf][s][d], physical chunk = logical ^ (s&7)
  __shared__ short Vs[2][64][64];   // [buf][d][s], physical chunk = logical ^ (d&7)
  __shared__ short Ps[128][64];     // [t][s], per-wave 16-row stripes, same swizzle
  const int tid = threadIdx.x, lane = tid & 63, wid = tid >> 6;
  const int bh = blockIdx.y;
  const int b = bh >> 4, h = bh & 15;
  const int t0 = blockIdx.x * 128;
  const int tw = t0 + wid * 16;
  const int r16 = lane & 15, kg = lane >> 4;
  const int x7 = r16 & 7;
  const int ph0 = (kg ^ x7) * 8;
  const int ph1 = ((kg + 4) ^ x7) * 8;

  const int sR = tid >> 3;
  const int sL = (tid & 7) ^ (sR & 7);

  const unsigned short* kbase = kh + (size_t)bh * 2048 * 64;
  const unsigned short* vtb   = vhT + (size_t)bh * 64 * 2048;
  const unsigned short* qbase = qh + ((size_t)bh * 2048 + tw) * 64;

  // Q fragment (pre-scaled by 0.125*log2e in the GEMM): serves as MFMA B operand.
  bf16x8 aq[2];
  aq[0] = *(const bf16x8*)(qbase + (size_t)r16 * 64 + kg * 8);
  aq[1] = *(const bf16x8*)(qbase + (size_t)r16 * 64 + 32 + kg * 8);

  // per-lane softmax state for q-row (tw + r16)
  float m_r = -INFINITY, l_r = 0.f;
  f32x4 o[4];   // O rows tw + kg*4 + r, cols df*16 + r16
  const f32x4 z4 = {0.f, 0.f, 0.f, 0.f};
  #pragma unroll
  for (int df = 0; df < 4; ++df) o[df] = z4;

  const unsigned long long* mrow = mbits + (size_t)(tw + r16) * 32;

  // prologue: stage chunk 0 into buf 0
  gload16(kbase + (size_t)sR * 64 + sL * 8, (char*)Ks + wid * 1024);
  gload16(vtb + (size_t)sR * 2048 + sL * 8, (char*)Vs + wid * 1024);
  __syncthreads();

  for (int c = 0; c < 32; ++c) {
    const int cur = c & 1;
    const int s0n = (c + 1) * 64;
    if (c + 1 < 32) {
      gload16(kbase + (size_t)(s0n + sR) * 64 + sL * 8, (char*)Ks + (cur ^ 1) * 8192 + wid * 1024);
      gload16(vtb + (size_t)sR * 2048 + s0n + sL * 8, (char*)Vs + (cur ^ 1) * 8192 + wid * 1024);
    }

    // swapped QK^T: sfr[sb][r] = S[s = sb*16+kg*4+r][q-row = tw+r16] (log2-domain)
    f32x4 sfr[4];
    __builtin_amdgcn_s_setprio(1);
    #pragma unroll
    for (int sb = 0; sb < 4; ++sb){
      bf16x8 bk0 = *(const bf16x8*)&Ks[cur][sb*16 + r16][ph0];
      bf16x8 bk1 = *(const bf16x8*)&Ks[cur][sb*16 + r16][ph1];
      f32x4 z = z4;
      z = __builtin_amdgcn_mfma_f32_16x16x32_bf16(bk0, aq[0], z, 0, 0, 0);
      z = __builtin_amdgcn_mfma_f32_16x16x32_bf16(bk1, aq[1], z, 0, 0, 0);
      sfr[sb] = z;
    }
    __builtin_amdgcn_s_setprio(0);

    // mask (one u64 for this lane's q-row)
    unsigned long long mwk = mrow[c] >> (kg * 4);
    #pragma unroll
    for (int sb = 0; sb < 4; ++sb)
      #pragma unroll
      for (int r = 0; r < 4; ++r)
        if ((mwk >> (sb * 16 + r)) & 1ull) sfr[sb][r] = MASKVAL;

    // in-register row max over 16 values + 2-step cross-kg reduce
    float mxa = fmaxf(fmaxf(sfr[0][0], sfr[0][1]), fmaxf(sfr[0][2], sfr[0][3]));
    float mxb = fmaxf(fmaxf(sfr[1][0], sfr[1][1]), fmaxf(sfr[1][2], sfr[1][3]));
    float mxc = fmaxf(fmaxf(sfr[2][0], sfr[2][1]), fmaxf(sfr[2][2], sfr[2][3]));
    float mxd = fmaxf(fmaxf(sfr[3][0], sfr[3][1]), fmaxf(sfr[3][2], sfr[3][3]));
    float mx = fmaxf(fmaxf(mxa, mxb), fmaxf(mxc, mxd));
    mx = fmaxf(mx, __shfl_xor(mx, 16));
    mx = fmaxf(mx, __shfl_xor(mx, 32));

    float mn = fmaxf(m_r, mx);
    float corr = exp2f(m_r - mn);
    m_r = mn;

    #pragma unroll
    for (int sb = 0; sb < 4; ++sb)
      #pragma unroll
      for (int r = 0; r < 4; ++r)
        sfr[sb][r] = exp2f(sfr[sb][r] - mn);

    float s0 = (sfr[0][0] + sfr[0][1]) + (sfr[0][2] + sfr[0][3]);
    float s1 = (sfr[1][0] + sfr[1][1]) + (sfr[1][2] + sfr[1][3]);
    float s2 = (sfr[2][0] + sfr[2][1]) + (sfr[2][2] + sfr[2][3]);
    float s3 = (sfr[3][0] + sfr[3][1]) + (sfr[3][2] + sfr[3][3]);
    float rs = (s0 + s1) + (s2 + s3);
    rs += __shfl_xor(rs, 16);
    rs += __shfl_xor(rs, 32);
    l_r = l_r * corr + rs;

    // redistribute corr to o-rows (row kg*4+r is held by lane r16'=kg*4+r)
    float cv0 = __shfl(corr, kg * 20 + 0);
    float cv1 = __shfl(corr, kg * 20 + 1);
    float cv2 = __shfl(corr, kg * 20 + 2);
    float cv3 = __shfl(corr, kg * 20 + 3);
    #pragma unroll
    for (int df = 0; df < 4; ++df){
      o[df][0] *= cv0; o[df][1] *= cv1; o[df][2] *= cv2; o[df][3] *= cv3;
    }

    // P -> LDS: lane owns row r16 of its wave stripe, cols sb*16 + kg*4 + (0..3)
    #pragma unroll
    for (int sb = 0; sb < 4; ++sb){
      unsigned int lo = cvtpk_bf16(sfr[sb][0], sfr[sb][1]);
      unsigned int hi = cvtpk_bf16(sfr[sb][2], sfr[sb][3]);
      int phys = (sb * 2 + (kg >> 1)) ^ x7;
      uint2_t pk; pk[0] = lo; pk[1] = hi;
      *(uint2_t*)&Ps[wid*16 + r16][phys * 8 + (kg & 1) * 4] = pk;
    }

    // PV: o[t][d] += P[t][s] * V[s][d]
    bf16x8 pa0 = *(const bf16x8*)&Ps[wid*16 + r16][ph0];
    bf16x8 pa1 = *(const bf16x8*)&Ps[wid*16 + r16][ph1];
    __builtin_amdgcn_s_setprio(1);
    #pragma unroll
    for (int df = 0; df < 4; ++df){
      bf16x8 bv0 = *(const bf16x8*)&Vs[cur][df*16 + r16][ph0];
      bf16x8 bv1 = *(const bf16x8*)&Vs[cur][df*16 + r16][ph1];
      o[df] = __builtin_amdgcn_mfma_f32_16x16x32_bf16(pa0, bv0, o[df], 0, 0, 0);
      o[df] = __builtin_amdgcn_mfma_f32_16x16x32_bf16(pa1, bv1, o[df], 0, 0, 0);
    }
    __builtin_amdgcn_s_setprio(0);

    __syncthreads();
  }

  // epilogue: normalize (redistribute 1/l to o-rows), write [b*T+t][E] bf16
  float li = 1.0f / l_r;
  float lv0 = __shfl(li, kg * 20 + 0);
  float lv1 = __shfl(li, kg * 20 + 1);
  float lv2 = __shfl(li, kg * 20 + 2);
  float lv3 = __shfl(li, kg * 20 + 3);
  #pragma unroll
  for (int df = 0; df < 4; ++df){
    int col = h*64 + df*16 + r16;
    int t = tw + kg*4;
    attnout[(size_t)(b * 2048 + t + 0) * 1024 + col] = (short)f2b(o[df][0] * lv0);
    attnout[(size_t)(b * 2048 + t + 1) * 1024 + col] = (short)f2b(o[df][1] * lv1);
    attnout[(size_t)(b * 2048 + t + 2) * 1024 + col] = (short)f2b(o[df][2] * lv2);
    attnout[(size_t)(b * 2048 + t + 3) * 1024 + col] = (short)f2b(o[df][3] * lv3);
  }
}

// ---------------- launch ----------------
extern "C" void kernel_launch(void* const* d_in, const int* in_sizes, int n_in,
                              void* d_out, int out_size, void* d_ws, size_t ws_size,
                              hipStream_t stream) {
  const float* q    = (const float*)d_in[0];
  const float* k    = (const float*)d_in[1];
  const float* v    = (const float*)d_in[2];
  const int*   mask = (const int*)d_in[3];
  const float* Wq = (const float*)d_in[4];  const float* bq = (const float*)d_in[5];
  const float* Wk = (const float*)d_in[6];  const float* bk = (const float*)d_in[7];
  const float* Wv = (const float*)d_in[8];  const float* bv = (const float*)d_in[9];
  const float* Wo = (const float*)d_in[10]; const float* bo = (const float*)d_in[11];

  char* ws = (char*)d_ws;
  unsigned short* qb   = (unsigned short*)(ws);                   // 8 MB [4096][1024] bf16
  unsigned short* kb   = (unsigned short*)(ws + 8388608);         // 8 MB
  unsigned short* vb   = (unsigned short*)(ws + 16777216);        // 8 MB
  unsigned short* Wqb  = (unsigned short*)(ws + 25165824);        // 2 MB
  unsigned short* Wkb  = (unsigned short*)(ws + 27262976);        // 2 MB
  unsigned short* Wvb  = (unsigned short*)(ws + 29360128);        // 2 MB
  unsigned short* Wob  = (unsigned short*)(ws + 31457280);        // 2 MB
  unsigned short* qhd  = (unsigned short*)(ws + 33554432);        // 8 MB [bh][t][64]
  unsigned short* khd  = (unsigned short*)(ws + 41943040);        // 8 MB [bh][s][64]
  unsigned short* vhT  = (unsigned short*)(ws + 50331648);        // 8 MB [bh][64][2048]
  unsigned long long* mbits = (unsigned long long*)(ws + 58720256); // 512 KB
  unsigned short* attno = qb;   // alias: qb dead after QKV GEMM

  maskbits_kernel<<<256, 256, 0, stream>>>(mask, mbits);

  CvtArgs ca;
  ca.src[0]=q;  ca.dst[0]=qb;  ca.src[1]=k;  ca.dst[1]=kb;  ca.src[2]=v;  ca.dst[2]=vb;
  ca.src[3]=Wq; ca.dst[3]=Wqb; ca.src[4]=Wk; ca.dst[4]=Wkb;
  ca.src[5]=Wv; ca.dst[5]=Wvb; ca.src[6]=Wo; ca.dst[6]=Wob;
  cvt_kernel<<<dim3(4096, 7), 256, 0, stream>>>(ca);

  GemmArgs g0;
  g0.A[0]=qb; g0.A[1]=kb; g0.A[2]=vb;
  g0.W[0]=Wqb; g0.W[1]=Wkb; g0.W[2]=Wvb;
  g0.bias[0]=bq; g0.bias[1]=bk; g0.bias[2]=bv;
  g0.C[0]=qhd; g0.C[1]=khd; g0.C[2]=vhT;
  gemm_kernel<0><<<dim3(32, 24), 256, 0, stream>>>(g0);

  attn_kernel<<<dim3(16, 32), 512, 0, stream>>>(qhd, khd, vhT, mbits, attno);

  GemmArgs g1;
  g1.A[0]=attno; g1.A[1]=attno; g1.A[2]=attno;
  g1.W[0]=Wob; g1.W[1]=Wob; g1.W[2]=Wob;
  g1.bias[0]=bo; g1.bias[1]=bo; g1.bias[2]=bo;
  g1.C[0]=d_out; g1.C[1]=d_out; g1.C[2]=d_out;
  gemm_kernel<1><<<dim3(32, 8), 256, 0, stream>>>(g1);
}

// Round 5
// 163.763 us; speedup vs baseline: 2.0825x; 1.0528x over previous
//
#include <hip/hip_runtime.h>
#include <hip/hip_bf16.h>
#include <math.h>

#define QSCALE 0.18033688011112042f   /* 0.125 * log2(e) */
#define MASKVAL -14426.950408889634f  /* -10000 * log2(e) */

typedef __attribute__((ext_vector_type(4))) float f32x4;
typedef __attribute__((ext_vector_type(8))) short bf16x8;
typedef __attribute__((ext_vector_type(4))) short bf16x4;
typedef __attribute__((ext_vector_type(4))) float float4_t;
typedef __attribute__((ext_vector_type(4))) int int4_t;
typedef __attribute__((ext_vector_type(2))) unsigned int uint2_t;

typedef const __attribute__((address_space(1))) void gbl_cvoid;
typedef __attribute__((address_space(3))) void lds_void;

static __device__ __forceinline__ void gload16(const void* g, void* l){
  __builtin_amdgcn_global_load_lds((gbl_cvoid*)g, (lds_void*)l, 16, 0, 0);
}

static __device__ __forceinline__ unsigned short f2b(float f){
  unsigned int u = __builtin_bit_cast(unsigned int, f);
  u = (u + 0x7FFFu + ((u >> 16) & 1u)) >> 16;
  return (unsigned short)u;
}

static __device__ __forceinline__ unsigned int cvtpk_bf16(float a, float b){
  unsigned int r;
  asm("v_cvt_pk_bf16_f32 %0, %1, %2" : "=v"(r) : "v"(a), "v"(b));
  return r;
}

// ---------------- fp32->bf16 cvt (7 tensors) + mask->bits, one dispatch ----------------
struct CvtArgs { const float* src[7]; unsigned short* dst[7]; };

__global__ __launch_bounds__(256) void cvt_kernel(CvtArgs a, const int* __restrict__ mask,
                                                  unsigned long long* __restrict__ mout){
  int y = blockIdx.y;
  if (y == 7){
    if (blockIdx.x >= 256) return;
    int w = blockIdx.x * 256 + threadIdx.x;      // = t*32 + (s>>6)
    const int* p = mask + (size_t)w * 64;
    unsigned long long bits = 0ull;
    #pragma unroll
    for (int j = 0; j < 64; j += 4){
      int4_t v4 = *(const int4_t*)(p + j);
      if (v4[0]) bits |= (1ull << (j + 0));
      if (v4[1]) bits |= (1ull << (j + 1));
      if (v4[2]) bits |= (1ull << (j + 2));
      if (v4[3]) bits |= (1ull << (j + 3));
    }
    mout[w] = bits;
    return;
  }
  int n4 = (y < 3) ? (4194304/4) : (1048576/4);
  int idx = blockIdx.x * 256 + threadIdx.x;
  if (idx >= n4) return;
  float4_t v = *(const float4_t*)(a.src[y] + (size_t)idx * 4);
  bf16x4 b; b[0]=(short)f2b(v[0]); b[1]=(short)f2b(v[1]); b[2]=(short)f2b(v[2]); b[3]=(short)f2b(v[3]);
  *(bf16x4*)(a.dst[y] + (size_t)idx * 4) = b;
}

// ---------------- bf16 GEMM: C[m,n] = sum_k A[m,k]*W[n,k] + bias[n] ----------------
// BK=64, XOR chunk-swizzle (phys chunk = logical ^ (row&7)), gload_lds staging.
struct GemmArgs { const unsigned short* A[3]; const unsigned short* W[3];
                  const float* bias[3]; void* C[3]; };

template<int MODE>
__global__ __launch_bounds__(256) void gemm_kernel(GemmArgs ga)
{
  __shared__ unsigned short As[128*64];
  __shared__ unsigned short Ws[128*64];
  const int tid = threadIdx.x, lane = tid & 63, wid = tid >> 6;
  const int sel = (MODE == 0) ? (blockIdx.y >> 3) : 0;
  const int n0  = (MODE == 0) ? ((blockIdx.y & 7) * 128) : (blockIdx.y * 128);
  const int m0  = blockIdx.x * 128;
  const unsigned short* A = ga.A[sel];
  const unsigned short* W = ga.W[sel];
  const float* bias = ga.bias[sel];
  const int wm = wid >> 1, wn = wid & 1;
  const int r16 = lane & 15, kg = lane >> 4;
  const int x7 = r16 & 7;
  const int sR = tid >> 3;                 // 0..31
  const int sL = (tid & 7) ^ (sR & 7);     // logical chunk for this slot (row&7 == sR&7)

  f32x4 acc[4][4];
  const f32x4 z4 = {0.f, 0.f, 0.f, 0.f};
  #pragma unroll
  for (int i = 0; i < 4; ++i)
    #pragma unroll
    for (int j = 0; j < 4; ++j) acc[i][j] = z4;

  for (int k0 = 0; k0 < 1024; k0 += 64) {
    #pragma unroll
    for (int i = 0; i < 4; ++i){
      int row = i * 32 + sR;
      gload16(A + (size_t)(m0 + row) * 1024 + k0 + sL * 8, (char*)As + i * 4096 + wid * 1024);
      gload16(W + (size_t)(n0 + row) * 1024 + k0 + sL * 8, (char*)Ws + i * 4096 + wid * 1024);
    }
    __syncthreads();
    #pragma unroll
    for (int kk = 0; kk < 2; ++kk){
      bf16x8 af[4], wf[4];
      #pragma unroll
      for (int mi = 0; mi < 4; ++mi)
        af[mi] = *(const bf16x8*)(As + (wm*64 + mi*16 + r16)*64 + (((kk<<2) + kg) ^ x7)*8);
      #pragma unroll
      for (int ni = 0; ni < 4; ++ni)
        wf[ni] = *(const bf16x8*)(Ws + (wn*64 + ni*16 + r16)*64 + (((kk<<2) + kg) ^ x7)*8);
      #pragma unroll
      for (int mi = 0; mi < 4; ++mi)
        #pragma unroll
        for (int ni = 0; ni < 4; ++ni)
          acc[mi][ni] = __builtin_amdgcn_mfma_f32_16x16x32_bf16(af[mi], wf[ni], acc[mi][ni], 0, 0, 0);
    }
    __syncthreads();
  }

  #pragma unroll
  for (int mi = 0; mi < 4; ++mi){
    #pragma unroll
    for (int ni = 0; ni < 4; ++ni){
      int m = m0 + wm*64 + mi*16 + kg*4;
      int n = n0 + wn*64 + ni*16 + r16;
      float bv = bias[n];
      if (MODE == 0 && sel == 2){
        int bb = m >> 11, t = m & 2047, hh = n >> 6, d = n & 63;
        bf16x4 pk;
        #pragma unroll
        for (int r = 0; r < 4; ++r) pk[r] = (short)f2b(acc[mi][ni][r] + bv);
        *(bf16x4*)&((unsigned short*)ga.C[2])[((size_t)(bb*16 + hh) * 64 + d) * 2048 + t] = pk;
      } else {
        #pragma unroll
        for (int r = 0; r < 4; ++r){
          float v = acc[mi][ni][r] + bv;
          if (MODE == 0 && sel == 0) v *= QSCALE;
          int mm = m + r;
          if (MODE == 1){
            ((float*)ga.C[0])[(size_t)mm * 1024 + n] = v;
          } else {
            int bb = mm >> 11, t = mm & 2047, hh = n >> 6, d = n & 63;
            ((unsigned short*)ga.C[sel])[(((size_t)(bb*16 + hh) * 2048 + t) << 6) + d] = f2b(v);
          }
        }
      }
    }
  }
}

// ---------------- flash attention ----------------
// 512 thr = 8 waves x 16 q-rows; KV chunks 64, dbuf gload_lds, XOR swizzle,
// swapped QK^T (lane owns one q-row), sum-via-MFMA (ones operand), defer-max THR=8.
__global__ __launch_bounds__(512) void attn_kernel(const unsigned short* __restrict__ qh,
    const unsigned short* __restrict__ kh, const unsigned short* __restrict__ vhT,
    const unsigned long long* __restrict__ mbits, unsigned short* __restrict__ attnout)
{
  __shared__ short Ks[2][64][64];
  __shared__ short Vs[2][64][64];
  __shared__ short Ps[128][64];
  const int tid = threadIdx.x, lane = tid & 63, wid = tid >> 6;
  const int bh = blockIdx.y;
  const int b = bh >> 4, h = bh & 15;
  const int t0 = blockIdx.x * 128;
  const int tw = t0 + wid * 16;
  const int r16 = lane & 15, kg = lane >> 4;
  const int x7 = r16 & 7;
  const int ph0 = (kg ^ x7) * 8;
  const int ph1 = ((kg + 4) ^ x7) * 8;
  const int sR = tid >> 3;
  const int sL = (tid & 7) ^ (sR & 7);

  const unsigned short* kbase = kh + (size_t)bh * 2048 * 64;
  const unsigned short* vtb   = vhT + (size_t)bh * 64 * 2048;
  const unsigned short* qbase = qh + ((size_t)bh * 2048 + tw) * 64;

  bf16x8 aq[2];
  aq[0] = *(const bf16x8*)(qbase + (size_t)r16 * 64 + kg * 8);
  aq[1] = *(const bf16x8*)(qbase + (size_t)r16 * 64 + 32 + kg * 8);

  const short ob = (short)0x3F80;
  const bf16x8 ones8 = {ob, ob, ob, ob, ob, ob, ob, ob};

  float m_r = -INFINITY;
  f32x4 o[4], o5;
  const f32x4 z4 = {0.f, 0.f, 0.f, 0.f};
  #pragma unroll
  for (int df = 0; df < 4; ++df) o[df] = z4;
  o5 = z4;

  const unsigned long long* mrow = mbits + (size_t)(tw + r16) * 32;

  gload16(kbase + (size_t)sR * 64 + sL * 8, (char*)Ks + wid * 1024);
  gload16(vtb + (size_t)sR * 2048 + sL * 8, (char*)Vs + wid * 1024);
  unsigned long long mw_cur = mrow[0];
  __syncthreads();

  for (int c = 0; c < 32; ++c) {
    const int cur = c & 1;
    const int s0n = (c + 1) * 64;
    unsigned long long mw_nxt = 0ull;
    if (c + 1 < 32) {
      gload16(kbase + (size_t)(s0n + sR) * 64 + sL * 8, (char*)Ks + (cur ^ 1) * 8192 + wid * 1024);
      gload16(vtb + (size_t)sR * 2048 + s0n + sL * 8, (char*)Vs + (cur ^ 1) * 8192 + wid * 1024);
      mw_nxt = mrow[c + 1];
    }

    // swapped QK^T: sfr[sb][r] = S[s = sb*16+kg*4+r][q-row = tw+r16] (log2 domain)
    f32x4 sfr[4];
    __builtin_amdgcn_s_setprio(1);
    #pragma unroll
    for (int sb = 0; sb < 4; ++sb){
      bf16x8 bk0 = *(const bf16x8*)&Ks[cur][sb*16 + r16][ph0];
      bf16x8 bk1 = *(const bf16x8*)&Ks[cur][sb*16 + r16][ph1];
      f32x4 z = z4;
      z = __builtin_amdgcn_mfma_f32_16x16x32_bf16(bk0, aq[0], z, 0, 0, 0);
      z = __builtin_amdgcn_mfma_f32_16x16x32_bf16(bk1, aq[1], z, 0, 0, 0);
      sfr[sb] = z;
    }
    __builtin_amdgcn_s_setprio(0);

    // additive mask: -14427 where bit set (exp2 underflows to exactly 0)
    {
      unsigned long long mwk = mw_cur >> (kg * 4);
      unsigned int mlo = (unsigned int)mwk;
      unsigned int mhi = (unsigned int)(mwk >> 32);
      #pragma unroll
      for (int sb = 0; sb < 4; ++sb){
        unsigned int wd = (sb < 2) ? mlo : mhi;
        const int base = (sb & 1) * 16;
        #pragma unroll
        for (int r = 0; r < 4; ++r){
          float bitf = (float)((wd >> (base + r)) & 1u);
          sfr[sb][r] = fmaf(bitf, MASKVAL, sfr[sb][r]);
        }
      }
    }

    // defer-max: rescale only when some row's local max exceeds m_r + 8
    float mx = fmaxf(
        fmaxf(fmaxf(fmaxf(sfr[0][0], sfr[0][1]), fmaxf(sfr[0][2], sfr[0][3])),
              fmaxf(fmaxf(sfr[1][0], sfr[1][1]), fmaxf(sfr[1][2], sfr[1][3]))),
        fmaxf(fmaxf(fmaxf(sfr[2][0], sfr[2][1]), fmaxf(sfr[2][2], sfr[2][3])),
              fmaxf(fmaxf(sfr[3][0], sfr[3][1]), fmaxf(sfr[3][2], sfr[3][3]))));
    if (__any(mx > m_r + 8.0f)) {
      float rmx = fmaxf(mx, __shfl_xor(mx, 16));
      rmx = fmaxf(rmx, __shfl_xor(rmx, 32));
      float mn = fmaxf(m_r, rmx);
      float corr = exp2f(m_r - mn);
      m_r = mn;
      float cv0 = __shfl(corr, kg * 20 + 0);
      float cv1 = __shfl(corr, kg * 20 + 1);
      float cv2 = __shfl(corr, kg * 20 + 2);
      float cv3 = __shfl(corr, kg * 20 + 3);
      #pragma unroll
      for (int df = 0; df < 4; ++df){
        o[df][0] *= cv0; o[df][1] *= cv1; o[df][2] *= cv2; o[df][3] *= cv3;
      }
      o5[0] *= cv0; o5[1] *= cv1; o5[2] *= cv2; o5[3] *= cv3;
    }

    // p = exp2(S - m), pack to bf16, write swizzled P stripe
    #pragma unroll
    for (int sb = 0; sb < 4; ++sb){
      float p0 = exp2f(sfr[sb][0] - m_r);
      float p1 = exp2f(sfr[sb][1] - m_r);
      float p2 = exp2f(sfr[sb][2] - m_r);
      float p3 = exp2f(sfr[sb][3] - m_r);
      unsigned int lo = cvtpk_bf16(p0, p1);
      unsigned int hi = cvtpk_bf16(p2, p3);
      int phys = (sb * 2 + (kg >> 1)) ^ x7;
      uint2_t pk; pk[0] = lo; pk[1] = hi;
      *(uint2_t*)&Ps[wid*16 + r16][phys * 8 + (kg & 1) * 4] = pk;
    }

    // PV + row-sum via MFMA (ones): o5[r] = running l for row kg*4+r (all lanes)
    bf16x8 pa0 = *(const bf16x8*)&Ps[wid*16 + r16][ph0];
    bf16x8 pa1 = *(const bf16x8*)&Ps[wid*16 + r16][ph1];
    __builtin_amdgcn_s_setprio(1);
    #pragma unroll
    for (int df = 0; df < 4; ++df){
      bf16x8 bv0 = *(const bf16x8*)&Vs[cur][df*16 + r16][ph0];
      bf16x8 bv1 = *(const bf16x8*)&Vs[cur][df*16 + r16][ph1];
      o[df] = __builtin_amdgcn_mfma_f32_16x16x32_bf16(pa0, bv0, o[df], 0, 0, 0);
      o[df] = __builtin_amdgcn_mfma_f32_16x16x32_bf16(pa1, bv1, o[df], 0, 0, 0);
    }
    o5 = __builtin_amdgcn_mfma_f32_16x16x32_bf16(pa0, ones8, o5, 0, 0, 0);
    o5 = __builtin_amdgcn_mfma_f32_16x16x32_bf16(pa1, ones8, o5, 0, 0, 0);
    __builtin_amdgcn_s_setprio(0);

    __syncthreads();
    mw_cur = mw_nxt;
  }

  // epilogue: every lane holds all 4 row-sums in o5
  float lv0 = 1.0f / o5[0];
  float lv1 = 1.0f / o5[1];
  float lv2 = 1.0f / o5[2];
  float lv3 = 1.0f / o5[3];
  #pragma unroll
  for (int df = 0; df < 4; ++df){
    int col = h*64 + df*16 + r16;
    int t = tw + kg*4;
    attnout[(size_t)(b * 2048 + t + 0) * 1024 + col] = (short)f2b(o[df][0] * lv0);
    attnout[(size_t)(b * 2048 + t + 1) * 1024 + col] = (short)f2b(o[df][1] * lv1);
    attnout[(size_t)(b * 2048 + t + 2) * 1024 + col] = (short)f2b(o[df][2] * lv2);
    attnout[(size_t)(b * 2048 + t + 3) * 1024 + col] = (short)f2b(o[df][3] * lv3);
  }
}

// ---------------- launch ----------------
extern "C" void kernel_launch(void* const* d_in, const int* in_sizes, int n_in,
                              void* d_out, int out_size, void* d_ws, size_t ws_size,
                              hipStream_t stream) {
  const float* q    = (const float*)d_in[0];
  const float* k    = (const float*)d_in[1];
  const float* v    = (const float*)d_in[2];
  const int*   mask = (const int*)d_in[3];
  const float* Wq = (const float*)d_in[4];  const float* bq = (const float*)d_in[5];
  const float* Wk = (const float*)d_in[6];  const float* bk = (const float*)d_in[7];
  const float* Wv = (const float*)d_in[8];  const float* bv = (const float*)d_in[9];
  const float* Wo = (const float*)d_in[10]; const float* bo = (const float*)d_in[11];

  char* ws = (char*)d_ws;
  unsigned short* qb   = (unsigned short*)(ws);                   // 8 MB [4096][1024] bf16
  unsigned short* kb   = (unsigned short*)(ws + 8388608);         // 8 MB
  unsigned short* vb   = (unsigned short*)(ws + 16777216);        // 8 MB
  unsigned short* Wqb  = (unsigned short*)(ws + 25165824);        // 2 MB
  unsigned short* Wkb  = (unsigned short*)(ws + 27262976);        // 2 MB
  unsigned short* Wvb  = (unsigned short*)(ws + 29360128);        // 2 MB
  unsigned short* Wob  = (unsigned short*)(ws + 31457280);        // 2 MB
  unsigned short* qhd  = (unsigned short*)(ws + 33554432);        // 8 MB [bh][t][64]
  unsigned short* khd  = (unsigned short*)(ws + 41943040);        // 8 MB [bh][s][64]
  unsigned short* vhT  = (unsigned short*)(ws + 50331648);        // 8 MB [bh][64][2048]
  unsigned long long* mbits = (unsigned long long*)(ws + 58720256); // 512 KB
  unsigned short* attno = qb;   // alias: qb dead after QKV GEMM

  CvtArgs ca;
  ca.src[0]=q;  ca.dst[0]=qb;  ca.src[1]=k;  ca.dst[1]=kb;  ca.src[2]=v;  ca.dst[2]=vb;
  ca.src[3]=Wq; ca.dst[3]=Wqb; ca.src[4]=Wk; ca.dst[4]=Wkb;
  ca.src[5]=Wv; ca.dst[5]=Wvb; ca.src[6]=Wo; ca.dst[6]=Wob;
  cvt_kernel<<<dim3(4096, 8), 256, 0, stream>>>(ca, mask, mbits);

  GemmArgs g0;
  g0.A[0]=qb; g0.A[1]=kb; g0.A[2]=vb;
  g0.W[0]=Wqb; g0.W[1]=Wkb; g0.W[2]=Wvb;
  g0.bias[0]=bq; g0.bias[1]=bk; g0.bias[2]=bv;
  g0.C[0]=qhd; g0.C[1]=khd; g0.C[2]=vhT;
  gemm_kernel<0><<<dim3(32, 24), 256, 0, stream>>>(g0);

  attn_kernel<<<dim3(16, 32), 512, 0, stream>>>(qhd, khd, vhT, mbits, attno);

  GemmArgs g1;
  g1.A[0]=attno; g1.A[1]=attno; g1.A[2]=attno;
  g1.W[0]=Wob; g1.W[1]=Wob; g1.W[2]=Wob;
  g1.bias[0]=bo; g1.bias[1]=bo; g1.bias[2]=bo;
  g1.C[0]=d_out; g1.C[1]=d_out; g1.C[2]=d_out;
  gemm_kernel<1><<<dim3(32, 8), 256, 0, stream>>>(g1);
}